// Round 4
// baseline (13816.699 us; speedup 1.0000x reference)
//
#include <hip/hip_runtime.h>
#include <hip/hip_bf16.h>
#include <stdint.h>

// LSTM decoder: H=1024, B=4096, T=128, IN=1.
// R4: persistent cooperative kernel, R2 block structure (256thr, 128x128 tile,
// swizzled global_load_lds w16). Per-batch-tile arrival counters replace the
// per-step grid-wide kernel boundary: a tile's 32 j-blocks sync only among
// themselves, so independent batch tiles drift across steps and overlap.

#define HH 1024
#define BB 4096
#define TT 128

#define BM 128   // batch rows per block
#define BKK 64   // K tile
#define NTILES 1024  // 32 jb x 32 bb

typedef __bf16 bf16;
typedef __bf16 v8bf __attribute__((ext_vector_type(8)));
typedef float f32x4 __attribute__((ext_vector_type(4)));

__device__ __forceinline__ float fast_sigmoid(float x) {
    return 1.0f / (1.0f + __expf(-x));
}
__device__ __forceinline__ float fast_tanh(float x) {
    return 1.0f - 2.0f / (__expf(2.0f * x) + 1.0f);
}

__device__ __forceinline__ void gload_lds16(const void* g, void* l) {
    __builtin_amdgcn_global_load_lds(
        (const __attribute__((address_space(1))) uint32_t*)(uintptr_t)g,
        (__attribute__((address_space(3))) uint32_t*)(uint32_t)(uintptr_t)l,
        16, 0, 0);
}

// ---- Prologue kernels ------------------------------------------------------

__global__ void prep_weights(const float* __restrict__ Whh,
                             const float* __restrict__ bih,
                             const float* __restrict__ bhh,
                             bf16* __restrict__ Wr,
                             float* __restrict__ bias) {
    int idx = blockIdx.x * blockDim.x + threadIdx.x;
    if (idx < 4 * HH * HH) {
        int k   = idx & (HH - 1);
        int row = idx >> 10;          // Wr row: jb*128 + g*32 + jj
        int jb  = row >> 7;
        int g   = (row >> 5) & 3;
        int jj  = row & 31;
        int srow = g * HH + jb * 32 + jj;
        Wr[idx] = (bf16)Whh[srow * HH + k];
    }
    if (idx < 4 * HH) bias[idx] = bih[idx] + bhh[idx];
}

__global__ void prep_h(const float* __restrict__ h0, bf16* __restrict__ hb) {
    int idx = blockIdx.x * blockDim.x + threadIdx.x;
    if (idx < BB * HH) hb[idx] = (bf16)h0[idx];
}

__global__ void prep_pred(float* __restrict__ predbuf, const float* __restrict__ b_out,
                          unsigned* __restrict__ cnt) {
    int idx = blockIdx.x * blockDim.x + threadIdx.x;
    if (idx < (TT + 1) * BB) predbuf[idx] = (idx < BB) ? 0.0f : b_out[0];
    if (idx < 32 * 16) cnt[idx] = 0u;
}

// ---- Persistent fused LSTM kernel -----------------------------------------
// Block processes tile v (jb = XCD-grouped, bb = v>>5) for every step t.
// Sync: arrival counter per bb; tile needs cnt[bb] >= 32*t before reading h_t.

__global__ __launch_bounds__(256, 4)
void lstm_persist(bf16* __restrict__ hb0, bf16* __restrict__ hb1,
                  const float* __restrict__ cell0, float* __restrict__ cbuf,
                  const bf16* __restrict__ Wr, const float* __restrict__ bias,
                  const float* __restrict__ Wih, const float* __restrict__ Wout,
                  float* __restrict__ predbuf, unsigned* __restrict__ cnt,
                  int nblocks) {
    __shared__ bf16 As[BM][BKK];   // h tile (16 KB), XOR-swizzled chunks
    __shared__ bf16 Bs[BM][BKK];   // weight tile (16 KB)

    const int tid   = threadIdx.x;
    const int lane  = tid & 63;
    const int w     = tid >> 6;
    const int waveM = w >> 1, waveN = w & 1;
    const int quad  = lane >> 4, l15 = lane & 15;

    const int r8  = lane >> 3;        // 0..7
    const int gc  = (lane & 7) ^ r8;  // swizzled global 16B-chunk index
    const int swr = l15 & 7;          // read-side swizzle key (row & 7)

    for (int t = 0; t < TT; t++) {
        const bf16* hread = (t & 1) ? hb1 : hb0;
        bf16*       hwrite = (t & 1) ? hb0 : hb1;
        const float* cin  = (t == 0) ? cell0 : cbuf;
        const float* pr   = predbuf + (size_t)t * BB;
        float*       pw   = predbuf + (size_t)(t + 1) * BB;

        for (int v = blockIdx.x; v < NTILES; v += nblocks) {
            const int jb     = (v & 7) * 4 + ((v >> 3) & 3); // XCD-grouped
            const int bb     = v >> 5;
            const int blockB = bb * BM;
            unsigned* arrive = &cnt[bb * 16];

            if (t > 0) {
                if (tid == 0) {
                    while (__hip_atomic_load(arrive, __ATOMIC_RELAXED,
                                             __HIP_MEMORY_SCOPE_AGENT) < 32u * (unsigned)t)
                        __builtin_amdgcn_s_sleep(2);
                }
                __syncthreads();
                __builtin_amdgcn_fence(__ATOMIC_ACQUIRE, "agent");
            }

            f32x4 acc[4][4];
#pragma unroll
            for (int mi = 0; mi < 4; mi++)
#pragma unroll
                for (int g = 0; g < 4; g++) acc[mi][g] = (f32x4){0.f, 0.f, 0.f, 0.f};

            const bf16* Asrc = hread + (size_t)blockB * HH;
            const bf16* Bsrc = Wr + (size_t)jb * 128 * HH;

            for (int k0 = 0; k0 < HH; k0 += BKK) {
#pragma unroll
                for (int c2 = 0; c2 < 4; c2++) {
                    const int rowb = w * 32 + c2 * 8;
                    gload_lds16(Asrc + (size_t)(rowb + r8) * HH + k0 + gc * 8, &As[rowb][0]);
                    gload_lds16(Bsrc + (size_t)(rowb + r8) * HH + k0 + gc * 8, &Bs[rowb][0]);
                }
                asm volatile("s_waitcnt vmcnt(0)" ::: "memory");
                __syncthreads();
#pragma unroll
                for (int kk = 0; kk < 2; kk++) {
                    v8bf a[4], b[4];
                    const int pch = ((kk * 4 + quad) ^ swr) * 8;
#pragma unroll
                    for (int mi = 0; mi < 4; mi++)
                        a[mi] = *(const v8bf*)&As[waveM * 64 + mi * 16 + l15][pch];
#pragma unroll
                    for (int g = 0; g < 4; g++)
                        b[g] = *(const v8bf*)&Bs[g * 32 + waveN * 16 + l15][pch];
#pragma unroll
                    for (int mi = 0; mi < 4; mi++)
#pragma unroll
                        for (int g = 0; g < 4; g++)
                            acc[mi][g] = __builtin_amdgcn_mfma_f32_16x16x32_bf16(
                                a[mi], b[g], acc[mi][g], 0, 0, 0);
                }
                __syncthreads();
            }

            // Epilogue: acc[mi][0..3][r] = gates i,f,g,o at (batch, j):
            //   batch = blockB + waveM*64 + mi*16 + quad*4 + r
            //   j     = jb*32 + waveN*16 + l15
            const int jj = jb * 32 + waveN * 16 + l15;
            float wih[4], bsv[4];
#pragma unroll
            for (int g = 0; g < 4; g++) {
                wih[g] = Wih[g * HH + jj];
                bsv[g] = bias[g * HH + jj];
            }
            const float wo = Wout[jj];

#pragma unroll
            for (int mi = 0; mi < 4; mi++) {
#pragma unroll
                for (int r = 0; r < 4; r++) {
                    const int b = blockB + waveM * 64 + mi * 16 + quad * 4 + r;
                    const float x = pr[b];
                    const float gi = acc[mi][0][r] + x * wih[0] + bsv[0];
                    const float gf = acc[mi][1][r] + x * wih[1] + bsv[1];
                    const float gg = acc[mi][2][r] + x * wih[2] + bsv[2];
                    const float go = acc[mi][3][r] + x * wih[3] + bsv[3];
                    const float cn = fast_sigmoid(gf) * cin[(size_t)b * HH + jj]
                                   + fast_sigmoid(gi) * fast_tanh(gg);
                    cbuf[(size_t)b * HH + jj] = cn;
                    const float hn = fast_sigmoid(go) * fast_tanh(cn);
                    hwrite[(size_t)b * HH + jj] = (bf16)hn;
                    float p = hn * wo;
                    p += __shfl_xor(p, 1);
                    p += __shfl_xor(p, 2);
                    p += __shfl_xor(p, 4);
                    p += __shfl_xor(p, 8);
                    if (l15 == 0) atomicAdd(&pw[b], p);
                }
            }

            __syncthreads();  // all threads' stores drained (also guards LDS reuse)
            if (t + 1 < TT && tid == 0) {
                __builtin_amdgcn_fence(__ATOMIC_RELEASE, "agent");
                __hip_atomic_fetch_add(arrive, 1u, __ATOMIC_RELAXED,
                                       __HIP_MEMORY_SCOPE_AGENT);
            }
        }
    }
}

// ---- Output transpose: out[b][t] = pred_t[b] ------------------------------

__global__ void write_out(const float* __restrict__ predbuf, float* __restrict__ out) {
    int idx = blockIdx.x * blockDim.x + threadIdx.x;
    if (idx < BB * TT) {
        int t = idx & (TT - 1);
        int b = idx >> 7;
        out[idx] = predbuf[(size_t)(t + 1) * BB + b];
    }
}

// ---- Host launch -----------------------------------------------------------

extern "C" void kernel_launch(void* const* d_in, const int* in_sizes, int n_in,
                              void* d_out, int out_size, void* d_ws, size_t ws_size,
                              hipStream_t stream) {
    const float* hidden = (const float*)d_in[0];
    const float* cell   = (const float*)d_in[1];
    const float* Wih    = (const float*)d_in[2];
    const float* Whh    = (const float*)d_in[3];
    const float* bih    = (const float*)d_in[4];
    const float* bhh    = (const float*)d_in[5];
    const float* Wout   = (const float*)d_in[6];
    const float* bout   = (const float*)d_in[7];
    float* out = (float*)d_out;

    char* ws = (char*)d_ws;
    bf16* Wr = (bf16*)ws;        ws += (size_t)4 * HH * HH * 2;   // 8 MB
    bf16* hb0 = (bf16*)ws;       ws += (size_t)BB * HH * 2;       // 8 MB
    bf16* hb1 = (bf16*)ws;       ws += (size_t)BB * HH * 2;       // 8 MB
    float* cbuf = (float*)ws;    ws += (size_t)BB * HH * 4;       // 16 MB
    float* bias = (float*)ws;    ws += (size_t)4 * HH * 4;        // 16 KB
    float* predbuf = (float*)ws; ws += (size_t)(TT + 1) * BB * 4; // 2.1 MB
    unsigned* cnt = (unsigned*)ws; ws += 32 * 16 * 4;             // 2 KB

    prep_weights<<<(4 * HH * HH + 255) / 256, 256, 0, stream>>>(Whh, bih, bhh, Wr, bias);
    prep_h<<<(BB * HH + 255) / 256, 256, 0, stream>>>(hidden, hb0);
    prep_pred<<<((TT + 1) * BB + 255) / 256, 256, 0, stream>>>(predbuf, bout, cnt);

    int occ = 0;
    hipError_t e = hipOccupancyMaxActiveBlocksPerMultiprocessor(&occ, lstm_persist, 256, 0);
    int nblocks = (e == hipSuccess && occ > 0) ? occ * 256 : 512;
    if (nblocks > NTILES) nblocks = NTILES;

    const float* cell0 = cell;
    void* kargs[] = {
        (void*)&hb0, (void*)&hb1, (void*)&cell0, (void*)&cbuf,
        (void*)&Wr,  (void*)&bias, (void*)&Wih,  (void*)&Wout,
        (void*)&predbuf, (void*)&cnt, (void*)&nblocks
    };
    hipLaunchCooperativeKernel((const void*)lstm_persist, dim3(nblocks), dim3(256),
                               kargs, 0, stream);

    write_out<<<(BB * TT + 255) / 256, 256, 0, stream>>>(predbuf, out);
}

// Round 5
// 11964.860 us; speedup vs baseline: 1.1548x; 1.1548x over previous
//
#include <hip/hip_runtime.h>
#include <hip/hip_bf16.h>
#include <stdint.h>

// LSTM decoder: H=1024, B=4096, T=128, IN=1.
// R5 = R2 base (per-step 128x128 MFMA kernels, swizzled global_load_lds for
// weights, XCD-grouped jb) + A-operand (h) loaded DIRECT global->VGPR in MFMA
// fragment layout, removing A from LDS: halves LDS traffic and barrier drain.

#define HH 1024
#define BB 4096
#define TT 128

#define BM 128   // batch rows per block
#define BKK 64   // K tile

typedef __bf16 bf16;
typedef __bf16 v8bf __attribute__((ext_vector_type(8)));
typedef float f32x4 __attribute__((ext_vector_type(4)));

__device__ __forceinline__ float fast_sigmoid(float x) {
    return 1.0f / (1.0f + __expf(-x));
}
__device__ __forceinline__ float fast_tanh(float x) {
    return 1.0f - 2.0f / (__expf(2.0f * x) + 1.0f);
}

__device__ __forceinline__ void gload_lds16(const void* g, void* l) {
    __builtin_amdgcn_global_load_lds(
        (const __attribute__((address_space(1))) uint32_t*)(uintptr_t)g,
        (__attribute__((address_space(3))) uint32_t*)(uint32_t)(uintptr_t)l,
        16, 0, 0);
}

// ---- Prologue kernels ------------------------------------------------------

__global__ void prep_weights(const float* __restrict__ Whh,
                             const float* __restrict__ bih,
                             const float* __restrict__ bhh,
                             bf16* __restrict__ Wr,
                             float* __restrict__ bias) {
    int idx = blockIdx.x * blockDim.x + threadIdx.x;
    if (idx < 4 * HH * HH) {
        int k   = idx & (HH - 1);
        int row = idx >> 10;          // Wr row: jb*128 + g*32 + jj
        int jb  = row >> 7;
        int g   = (row >> 5) & 3;
        int jj  = row & 31;
        int srow = g * HH + jb * 32 + jj;
        Wr[idx] = (bf16)Whh[srow * HH + k];
    }
    if (idx < 4 * HH) bias[idx] = bih[idx] + bhh[idx];
}

__global__ void prep_h(const float* __restrict__ h0, bf16* __restrict__ hb) {
    int idx = blockIdx.x * blockDim.x + threadIdx.x;
    if (idx < BB * HH) hb[idx] = (bf16)h0[idx];
}

__global__ void prep_pred(float* __restrict__ predbuf, const float* __restrict__ b_out) {
    int idx = blockIdx.x * blockDim.x + threadIdx.x;
    if (idx < (TT + 1) * BB) predbuf[idx] = (idx < BB) ? 0.0f : b_out[0];
}

// ---- Per-step fused GEMM + cell update ------------------------------------

__global__ __launch_bounds__(256, 3)
void lstm_step(const bf16* __restrict__ hread, bf16* __restrict__ hwrite,
               const float* __restrict__ cin, float* __restrict__ cout,
               const bf16* __restrict__ Wr, const float* __restrict__ bias,
               const float* __restrict__ Wih, const float* __restrict__ Wout,
               const float* __restrict__ predbuf_r, float* __restrict__ predbuf_w) {
    // B only in LDS: unpadded, XOR-swizzled (phys 16B-chunk = logical ^ (row&7))
    __shared__ bf16 Bs[BM][BKK];   // weights: (4g x 32j) x k (16 KB)

    const int tid   = threadIdx.x;
    const int lane  = tid & 63;
    const int w     = tid >> 6;
    const int waveM = w >> 1, waveN = w & 1;
    const int quad  = lane >> 4, l15 = lane & 15;

    const int bid    = blockIdx.x;
    const int jb     = (bid & 7) * 4 + ((bid >> 3) & 3); // 0..31, XCD-grouped
    const int blockB = (bid >> 5) * BM;                  // batch base

    f32x4 acc[4][4]; // [m-tile][gate]
#pragma unroll
    for (int mi = 0; mi < 4; mi++)
#pragma unroll
        for (int g = 0; g < 4; g++) acc[mi][g] = (f32x4){0.f, 0.f, 0.f, 0.f};

    const bf16* Asrc = hread + (size_t)blockB * HH;
    const bf16* Bsrc = Wr + (size_t)jb * 128 * HH;

    const int r8  = lane >> 3;        // 0..7
    const int gc  = (lane & 7) ^ r8;  // swizzled global 16B-chunk for staging
    const int swr = l15 & 7;          // read-side swizzle key (row & 7)

    // per-lane A row base (row = waveM*64 + mi*16 + l15), fragment layout:
    // 16 B at column k0 + (kk*4+quad)*8 — 16 rows x 64 B coalesced per inst.
    const bf16* arow = Asrc + (size_t)(waveM * 64 + l15) * HH + quad * 8;

    for (int k0 = 0; k0 < HH; k0 += BKK) {
        // A fragments direct to registers (8 x global_load_dwordx4)
        v8bf a[2][4];
#pragma unroll
        for (int kk = 0; kk < 2; kk++)
#pragma unroll
            for (int mi = 0; mi < 4; mi++)
                a[kk][mi] = *(const v8bf*)(arow + (size_t)mi * 16 * HH + k0 + kk * 32);
        // B staging: wave w stages weight rows [w*32, w*32+32)
#pragma unroll
        for (int c2 = 0; c2 < 4; c2++) {
            const int rowb = w * 32 + c2 * 8;
            gload_lds16(Bsrc + (size_t)(rowb + r8) * HH + k0 + gc * 8, &Bs[rowb][0]);
        }
        asm volatile("s_waitcnt vmcnt(0)" ::: "memory");
        __syncthreads();
#pragma unroll
        for (int kk = 0; kk < 2; kk++) {
            v8bf b[4];
            const int pch = ((kk * 4 + quad) ^ swr) * 8;
#pragma unroll
            for (int g = 0; g < 4; g++)
                b[g] = *(const v8bf*)&Bs[g * 32 + waveN * 16 + l15][pch];
#pragma unroll
            for (int mi = 0; mi < 4; mi++)
#pragma unroll
                for (int g = 0; g < 4; g++)
                    acc[mi][g] = __builtin_amdgcn_mfma_f32_16x16x32_bf16(
                        a[kk][mi], b[g], acc[mi][g], 0, 0, 0);
        }
        __syncthreads();
    }

    // Epilogue: acc[mi][0..3][r] = gates i,f,g,o at (batch, j):
    //   batch = blockB + waveM*64 + mi*16 + quad*4 + r
    //   j     = jb*32 + waveN*16 + l15
    const int jj = jb * 32 + waveN * 16 + l15;
    float wih[4], bsv[4];
#pragma unroll
    for (int g = 0; g < 4; g++) {
        wih[g] = Wih[g * HH + jj];
        bsv[g] = bias[g * HH + jj];
    }
    const float wo = Wout[jj];

#pragma unroll
    for (int mi = 0; mi < 4; mi++) {
#pragma unroll
        for (int r = 0; r < 4; r++) {
            const int b = blockB + waveM * 64 + mi * 16 + quad * 4 + r;
            const float x = predbuf_r[b];  // pred_{t-1} (incl. b_out) or 0 at t=0
            const float gi = acc[mi][0][r] + x * wih[0] + bsv[0];
            const float gf = acc[mi][1][r] + x * wih[1] + bsv[1];
            const float gg = acc[mi][2][r] + x * wih[2] + bsv[2];
            const float go = acc[mi][3][r] + x * wih[3] + bsv[3];
            const float cn = fast_sigmoid(gf) * cin[(size_t)b * HH + jj]
                           + fast_sigmoid(gi) * fast_tanh(gg);
            cout[(size_t)b * HH + jj] = cn;
            const float hn = fast_sigmoid(go) * fast_tanh(cn);
            hwrite[(size_t)b * HH + jj] = (bf16)hn;
            float p = hn * wo;
            p += __shfl_xor(p, 1);
            p += __shfl_xor(p, 2);
            p += __shfl_xor(p, 4);
            p += __shfl_xor(p, 8);
            if (l15 == 0) atomicAdd(&predbuf_w[b], p);
        }
    }
}

// ---- Output transpose: out[b][t] = pred_t[b] ------------------------------

__global__ void write_out(const float* __restrict__ predbuf, float* __restrict__ out) {
    int idx = blockIdx.x * blockDim.x + threadIdx.x;
    if (idx < BB * TT) {
        int t = idx & (TT - 1);
        int b = idx >> 7;
        out[idx] = predbuf[(size_t)(t + 1) * BB + b];
    }
}

// ---- Host launch -----------------------------------------------------------

extern "C" void kernel_launch(void* const* d_in, const int* in_sizes, int n_in,
                              void* d_out, int out_size, void* d_ws, size_t ws_size,
                              hipStream_t stream) {
    const float* hidden = (const float*)d_in[0];
    const float* cell   = (const float*)d_in[1];
    const float* Wih    = (const float*)d_in[2];
    const float* Whh    = (const float*)d_in[3];
    const float* bih    = (const float*)d_in[4];
    const float* bhh    = (const float*)d_in[5];
    const float* Wout   = (const float*)d_in[6];
    const float* bout   = (const float*)d_in[7];
    float* out = (float*)d_out;

    char* ws = (char*)d_ws;
    bf16* Wr = (bf16*)ws;        ws += (size_t)4 * HH * HH * 2;   // 8 MB
    bf16* hb0 = (bf16*)ws;       ws += (size_t)BB * HH * 2;       // 8 MB
    bf16* hb1 = (bf16*)ws;       ws += (size_t)BB * HH * 2;       // 8 MB
    float* cbuf = (float*)ws;    ws += (size_t)BB * HH * 4;       // 16 MB
    float* bias = (float*)ws;    ws += (size_t)4 * HH * 4;        // 16 KB
    float* predbuf = (float*)ws; ws += (size_t)(TT + 1) * BB * 4; // 2.1 MB

    prep_weights<<<(4 * HH * HH + 255) / 256, 256, 0, stream>>>(Whh, bih, bhh, Wr, bias);
    prep_h<<<(BB * HH + 255) / 256, 256, 0, stream>>>(hidden, hb0);
    prep_pred<<<((TT + 1) * BB + 255) / 256, 256, 0, stream>>>(predbuf, bout);

    bf16* hb[2] = {hb0, hb1};
    for (int t = 0; t < TT; t++) {
        const bf16* hr = hb[t & 1];
        bf16* hw = hb[(t + 1) & 1];
        const float* ci = (t == 0) ? cell : cbuf;
        lstm_step<<<32 * (BB / BM), 256, 0, stream>>>(
            hr, hw, ci, cbuf, Wr, bias, Wih, Wout,
            predbuf + (size_t)t * BB, predbuf + (size_t)(t + 1) * BB);
    }

    write_out<<<(BB * TT + 255) / 256, 256, 0, stream>>>(predbuf, out);
}

// Round 6
// 7249.969 us; speedup vs baseline: 1.9058x; 1.6503x over previous
//
#include <hip/hip_runtime.h>
#include <hip/hip_bf16.h>
#include <stdint.h>

// LSTM decoder: H=1024, B=4096, T=128, IN=1.
// R6 = R2 base + AITER-style software-pipelined K-loop:
//   BKK=32, 3 LDS buffers (48 KB, 3 blocks/CU), prefetch distance 2,
//   raw s_barrier (no __syncthreads drain), s_waitcnt vmcnt(4) mid-loop.
// Staging loads stay in flight across barriers -> exposed global latency ~0.

#define HH 1024
#define BB 4096
#define TT 128

#define BM 128   // batch rows per block (also 4g x 32j weight rows)
#define BKK 32   // K tile (one MFMA-K per iter)
#define NKT (HH / BKK)  // 32 k-iterations

typedef __bf16 bf16;
typedef __bf16 v8bf __attribute__((ext_vector_type(8)));
typedef float f32x4 __attribute__((ext_vector_type(4)));

__device__ __forceinline__ float fast_sigmoid(float x) {
    return 1.0f / (1.0f + __expf(-x));
}
__device__ __forceinline__ float fast_tanh(float x) {
    return 1.0f - 2.0f / (__expf(2.0f * x) + 1.0f);
}

__device__ __forceinline__ void gload_lds16(const void* g, void* l) {
    __builtin_amdgcn_global_load_lds(
        (const __attribute__((address_space(1))) uint32_t*)(uintptr_t)g,
        (__attribute__((address_space(3))) uint32_t*)(uint32_t)(uintptr_t)l,
        16, 0, 0);
}

// ---- Prologue kernels ------------------------------------------------------

__global__ void prep_weights(const float* __restrict__ Whh,
                             const float* __restrict__ bih,
                             const float* __restrict__ bhh,
                             bf16* __restrict__ Wr,
                             float* __restrict__ bias) {
    int idx = blockIdx.x * blockDim.x + threadIdx.x;
    if (idx < 4 * HH * HH) {
        int k   = idx & (HH - 1);
        int row = idx >> 10;          // Wr row: jb*128 + g*32 + jj
        int jb  = row >> 7;
        int g   = (row >> 5) & 3;
        int jj  = row & 31;
        int srow = g * HH + jb * 32 + jj;
        Wr[idx] = (bf16)Whh[srow * HH + k];
    }
    if (idx < 4 * HH) bias[idx] = bih[idx] + bhh[idx];
}

__global__ void prep_h(const float* __restrict__ h0, bf16* __restrict__ hb) {
    int idx = blockIdx.x * blockDim.x + threadIdx.x;
    if (idx < BB * HH) hb[idx] = (bf16)h0[idx];
}

__global__ void prep_pred(float* __restrict__ predbuf, const float* __restrict__ b_out) {
    int idx = blockIdx.x * blockDim.x + threadIdx.x;
    if (idx < (TT + 1) * BB) predbuf[idx] = (idx < BB) ? 0.0f : b_out[0];
}

// ---- Per-step fused GEMM + cell update ------------------------------------
// LDS rows are 64 B (32 bf16) = 4 x 16B chunks; XOR swizzle:
//   phys_chunk = logical_chunk ^ (row & 3)
// Stage call: 64 lanes x 16 B = 16 rows; lane L -> row base+(L>>2), phys chunk
// L&3, so global source chunk = (L&3) ^ ((L>>2)&3).

__global__ __launch_bounds__(256, 3)
void lstm_step(const bf16* __restrict__ hread, bf16* __restrict__ hwrite,
               const float* __restrict__ cin, float* __restrict__ cout,
               const bf16* __restrict__ Wr, const float* __restrict__ bias,
               const float* __restrict__ Wih, const float* __restrict__ Wout,
               const float* __restrict__ predbuf_r, float* __restrict__ predbuf_w) {
    __shared__ bf16 As[3][BM][BKK];   // 3 x 8 KB
    __shared__ bf16 Bs[3][BM][BKK];   // 3 x 8 KB   (48 KB total)

    const int tid   = threadIdx.x;
    const int lane  = tid & 63;
    const int w     = tid >> 6;
    const int waveM = w >> 1, waveN = w & 1;
    const int quad  = lane >> 4, l15 = lane & 15;

    const int bid    = blockIdx.x;
    const int jb     = (bid & 7) * 4 + ((bid >> 3) & 3); // 0..31, XCD-grouped
    const int blockB = (bid >> 5) * BM;                  // batch base

    f32x4 acc[4][4]; // [m-tile][gate]
#pragma unroll
    for (int mi = 0; mi < 4; mi++)
#pragma unroll
        for (int g = 0; g < 4; g++) acc[mi][g] = (f32x4){0.f, 0.f, 0.f, 0.f};

    const bf16* Asrc = hread + (size_t)blockB * HH;
    const bf16* Bsrc = Wr + (size_t)jb * 128 * HH;

    const int r16  = lane >> 2;                       // 0..15 (row within call)
    const int gcol = (((lane & 3) ^ (r16 & 3))) * 8;  // swizzled global col (elems)
    const int pch  = (quad ^ (l15 & 3)) * 8;          // read-side phys chunk (elems)

#define STAGE(buf, k0)                                                        \
    {                                                                         \
        _Pragma("unroll")                                                     \
        for (int c2 = 0; c2 < 2; c2++) {                                      \
            const int rowb = w * 32 + c2 * 16;                                \
            gload_lds16(Asrc + (size_t)(rowb + r16) * HH + (k0) + gcol,       \
                        &As[buf][rowb][0]);                                   \
            gload_lds16(Bsrc + (size_t)(rowb + r16) * HH + (k0) + gcol,       \
                        &Bs[buf][rowb][0]);                                   \
        }                                                                     \
    }

    STAGE(0, 0);
    STAGE(1, BKK);

#pragma unroll
    for (int kt = 0; kt < NKT; kt++) {
        // drain this wave's stage(kt) loads; keep stage(kt+1) in flight
        if (kt < NKT - 1) asm volatile("s_waitcnt vmcnt(4)" ::: "memory");
        else              asm volatile("s_waitcnt vmcnt(0)" ::: "memory");
        asm volatile("s_barrier" ::: "memory");   // buf[kt%3] ready block-wide
        if (kt + 2 < NKT) STAGE((kt + 2) % 3, (kt + 2) * BKK);

        const int cb = kt % 3;
        v8bf a[4], b[4];
#pragma unroll
        for (int mi = 0; mi < 4; mi++)
            a[mi] = *(const v8bf*)&As[cb][waveM * 64 + mi * 16 + l15][pch];
#pragma unroll
        for (int g = 0; g < 4; g++)
            b[g] = *(const v8bf*)&Bs[cb][g * 32 + waveN * 16 + l15][pch];
#pragma unroll
        for (int mi = 0; mi < 4; mi++)
#pragma unroll
            for (int g = 0; g < 4; g++)
                acc[mi][g] = __builtin_amdgcn_mfma_f32_16x16x32_bf16(
                    a[mi], b[g], acc[mi][g], 0, 0, 0);
    }
#undef STAGE

    // Epilogue: acc[mi][0..3][r] = gates i,f,g,o at (batch, j):
    //   batch = blockB + waveM*64 + mi*16 + quad*4 + r
    //   j     = jb*32 + waveN*16 + l15
    const int jj = jb * 32 + waveN * 16 + l15;
    float wih[4], bsv[4];
#pragma unroll
    for (int g = 0; g < 4; g++) {
        wih[g] = Wih[g * HH + jj];
        bsv[g] = bias[g * HH + jj];
    }
    const float wo = Wout[jj];

#pragma unroll
    for (int mi = 0; mi < 4; mi++) {
#pragma unroll
        for (int r = 0; r < 4; r++) {
            const int b = blockB + waveM * 64 + mi * 16 + quad * 4 + r;
            const float x = predbuf_r[b];  // pred_{t-1} (incl. b_out) or 0 at t=0
            const float gi = acc[mi][0][r] + x * wih[0] + bsv[0];
            const float gf = acc[mi][1][r] + x * wih[1] + bsv[1];
            const float gg = acc[mi][2][r] + x * wih[2] + bsv[2];
            const float go = acc[mi][3][r] + x * wih[3] + bsv[3];
            const float cn = fast_sigmoid(gf) * cin[(size_t)b * HH + jj]
                           + fast_sigmoid(gi) * fast_tanh(gg);
            cout[(size_t)b * HH + jj] = cn;
            const float hn = fast_sigmoid(go) * fast_tanh(cn);
            hwrite[(size_t)b * HH + jj] = (bf16)hn;
            float p = hn * wo;
            p += __shfl_xor(p, 1);
            p += __shfl_xor(p, 2);
            p += __shfl_xor(p, 4);
            p += __shfl_xor(p, 8);
            if (l15 == 0) atomicAdd(&predbuf_w[b], p);
        }
    }
}

// ---- Output transpose: out[b][t] = pred_t[b] ------------------------------

__global__ void write_out(const float* __restrict__ predbuf, float* __restrict__ out) {
    int idx = blockIdx.x * blockDim.x + threadIdx.x;
    if (idx < BB * TT) {
        int t = idx & (TT - 1);
        int b = idx >> 7;
        out[idx] = predbuf[(size_t)(t + 1) * BB + b];
    }
}

// ---- Host launch -----------------------------------------------------------

extern "C" void kernel_launch(void* const* d_in, const int* in_sizes, int n_in,
                              void* d_out, int out_size, void* d_ws, size_t ws_size,
                              hipStream_t stream) {
    const float* hidden = (const float*)d_in[0];
    const float* cell   = (const float*)d_in[1];
    const float* Wih    = (const float*)d_in[2];
    const float* Whh    = (const float*)d_in[3];
    const float* bih    = (const float*)d_in[4];
    const float* bhh    = (const float*)d_in[5];
    const float* Wout   = (const float*)d_in[6];
    const float* bout   = (const float*)d_in[7];
    float* out = (float*)d_out;

    char* ws = (char*)d_ws;
    bf16* Wr = (bf16*)ws;        ws += (size_t)4 * HH * HH * 2;   // 8 MB
    bf16* hb0 = (bf16*)ws;       ws += (size_t)BB * HH * 2;       // 8 MB
    bf16* hb1 = (bf16*)ws;       ws += (size_t)BB * HH * 2;       // 8 MB
    float* cbuf = (float*)ws;    ws += (size_t)BB * HH * 4;       // 16 MB
    float* bias = (float*)ws;    ws += (size_t)4 * HH * 4;        // 16 KB
    float* predbuf = (float*)ws; ws += (size_t)(TT + 1) * BB * 4; // 2.1 MB

    prep_weights<<<(4 * HH * HH + 255) / 256, 256, 0, stream>>>(Whh, bih, bhh, Wr, bias);
    prep_h<<<(BB * HH + 255) / 256, 256, 0, stream>>>(hidden, hb0);
    prep_pred<<<((TT + 1) * BB + 255) / 256, 256, 0, stream>>>(predbuf, bout);

    bf16* hb[2] = {hb0, hb1};
    for (int t = 0; t < TT; t++) {
        const bf16* hr = hb[t & 1];
        bf16* hw = hb[(t + 1) & 1];
        const float* ci = (t == 0) ? cell : cbuf;
        lstm_step<<<32 * (BB / BM), 256, 0, stream>>>(
            hr, hw, ci, cbuf, Wr, bias, Wih, Wout,
            predbuf + (size_t)t * BB, predbuf + (size_t)(t + 1) * BB);
    }

    write_out<<<(BB * TT + 255) / 256, 256, 0, stream>>>(predbuf, out);
}

// Round 7
// 5596.939 us; speedup vs baseline: 2.4686x; 1.2953x over previous
//
#include <hip/hip_runtime.h>
#include <hip/hip_bf16.h>
#include <stdint.h>

// LSTM decoder: H=1024, B=4096, T=128, IN=1.
// R7 = R2 machinery (BKK=64 conflict-free swizzle, vmcnt(0)+syncthreads,
// global_load_lds w16, XCD-grouped weights) with BJ=64: each block computes
// 256 weight rows (4 gates x 64 j) x 128 batch -> halves A(h)-staging traffic
// and per-CU barrier count; 64x128 wave tiles (acc[4][8]).

#define HH 1024
#define BB 4096
#define TT 128

#define BM 128   // batch rows per block
#define BKK 64   // K tile

typedef __bf16 bf16;
typedef __bf16 v8bf __attribute__((ext_vector_type(8)));
typedef float f32x4 __attribute__((ext_vector_type(4)));

__device__ __forceinline__ float fast_sigmoid(float x) {
    return 1.0f / (1.0f + __expf(-x));
}
__device__ __forceinline__ float fast_tanh(float x) {
    return 1.0f - 2.0f / (__expf(2.0f * x) + 1.0f);
}

__device__ __forceinline__ void gload_lds16(const void* g, void* l) {
    __builtin_amdgcn_global_load_lds(
        (const __attribute__((address_space(1))) uint32_t*)(uintptr_t)g,
        (__attribute__((address_space(3))) uint32_t*)(uint32_t)(uintptr_t)l,
        16, 0, 0);
}

// ---- Prologue kernels ------------------------------------------------------

// Wr row layout: jb2*256 + g*64 + jj  <->  Whh row g*HH + jb2*64 + jj
__global__ void prep_weights(const float* __restrict__ Whh,
                             const float* __restrict__ bih,
                             const float* __restrict__ bhh,
                             bf16* __restrict__ Wr,
                             float* __restrict__ bias) {
    int idx = blockIdx.x * blockDim.x + threadIdx.x;
    if (idx < 4 * HH * HH) {
        int k   = idx & (HH - 1);
        int row = idx >> 10;
        int jb2 = row >> 8;
        int g   = (row >> 6) & 3;
        int jj  = row & 63;
        int srow = g * HH + jb2 * 64 + jj;
        Wr[idx] = (bf16)Whh[srow * HH + k];
    }
    if (idx < 4 * HH) bias[idx] = bih[idx] + bhh[idx];
}

__global__ void prep_h(const float* __restrict__ h0, bf16* __restrict__ hb) {
    int idx = blockIdx.x * blockDim.x + threadIdx.x;
    if (idx < BB * HH) hb[idx] = (bf16)h0[idx];
}

__global__ void prep_pred(float* __restrict__ predbuf, const float* __restrict__ b_out) {
    int idx = blockIdx.x * blockDim.x + threadIdx.x;
    if (idx < (TT + 1) * BB) predbuf[idx] = (idx < BB) ? 0.0f : b_out[0];
}

// ---- Per-step fused GEMM + cell update ------------------------------------
// 512 blocks = 16 jb2 x 32 bb. Block tile: 128 batch x 256 weight rows.
// Wave w: batch half waveM=w>>1 (64 rows) x weight half waveN=w&1
// (j-quarters {2*waveN, 2*waveN+1} across all 4 gates) -> acc[4][g*2+jh].

__global__ __launch_bounds__(256, 2)
void lstm_step(const bf16* __restrict__ hread, bf16* __restrict__ hwrite,
               const float* __restrict__ cin, float* __restrict__ cout,
               const bf16* __restrict__ Wr, const float* __restrict__ bias,
               const float* __restrict__ Wih, const float* __restrict__ Wout,
               const float* __restrict__ predbuf_r, float* __restrict__ predbuf_w) {
    // unpadded 128-B rows, XOR-swizzled: phys 16B-chunk = logical ^ (row&7)
    __shared__ bf16 As[BM][BKK];        // h tile: 128 x 64      (16 KB)
    __shared__ bf16 Bs[2 * BM][BKK];    // weights: 256 x 64     (32 KB)

    const int tid   = threadIdx.x;
    const int lane  = tid & 63;
    const int w     = tid >> 6;
    const int waveM = w >> 1, waveN = w & 1;
    const int quad  = lane >> 4, l15 = lane & 15;

    const int bid    = blockIdx.x;
    const int jb2    = (bid & 7) * 2 + ((bid >> 3) & 1); // 0..15, XCD-grouped
    const int blockB = (bid >> 4) * BM;                  // batch base

    f32x4 acc[4][8]; // [m-tile][gate*2 + j-half]
#pragma unroll
    for (int mi = 0; mi < 4; mi++)
#pragma unroll
        for (int nt = 0; nt < 8; nt++) acc[mi][nt] = (f32x4){0.f, 0.f, 0.f, 0.f};

    const bf16* Asrc = hread + (size_t)blockB * HH;
    const bf16* Bsrc = Wr + (size_t)jb2 * 256 * HH;

    const int r8  = lane >> 3;        // 0..7
    const int gc  = (lane & 7) ^ r8;  // swizzled global 16B-chunk for staging
    const int swr = l15 & 7;          // read-side swizzle key (row & 7)

    for (int k0 = 0; k0 < HH; k0 += BKK) {
        // A: wave stages rows [w*32, w*32+32) — 4 calls (8 rows x 128 B each)
#pragma unroll
        for (int c2 = 0; c2 < 4; c2++) {
            const int rowb = w * 32 + c2 * 8;
            gload_lds16(Asrc + (size_t)(rowb + r8) * HH + k0 + gc * 8, &As[rowb][0]);
        }
        // B: wave stages rows [w*64, w*64+64) — 8 calls
#pragma unroll
        for (int c2 = 0; c2 < 8; c2++) {
            const int rowb = w * 64 + c2 * 8;
            gload_lds16(Bsrc + (size_t)(rowb + r8) * HH + k0 + gc * 8, &Bs[rowb][0]);
        }
        asm volatile("s_waitcnt vmcnt(0)" ::: "memory");
        __syncthreads();
#pragma unroll
        for (int kk = 0; kk < 2; kk++) {
            v8bf a[4], b[8];
            const int pch = ((kk * 4 + quad) ^ swr) * 8;
#pragma unroll
            for (int mi = 0; mi < 4; mi++)
                a[mi] = *(const v8bf*)&As[waveM * 64 + mi * 16 + l15][pch];
#pragma unroll
            for (int g = 0; g < 4; g++)
#pragma unroll
                for (int jh = 0; jh < 2; jh++)
                    b[g * 2 + jh] =
                        *(const v8bf*)&Bs[g * 64 + waveN * 32 + jh * 16 + l15][pch];
#pragma unroll
            for (int mi = 0; mi < 4; mi++)
#pragma unroll
                for (int nt = 0; nt < 8; nt++)
                    acc[mi][nt] = __builtin_amdgcn_mfma_f32_16x16x32_bf16(
                        a[mi], b[nt], acc[mi][nt], 0, 0, 0);
        }
        __syncthreads();
    }

    // Epilogue: acc[mi][g*2+jh][r] = gate g at (batch, j):
    //   batch = blockB + waveM*64 + mi*16 + quad*4 + r
    //   j     = jb2*64 + waveN*32 + jh*16 + l15
    float wihv[2][4], bsvv[2][4], wov[2];
#pragma unroll
    for (int jh = 0; jh < 2; jh++) {
        const int j = jb2 * 64 + waveN * 32 + jh * 16 + l15;
#pragma unroll
        for (int g = 0; g < 4; g++) {
            wihv[jh][g] = Wih[g * HH + j];
            bsvv[jh][g] = bias[g * HH + j];
        }
        wov[jh] = Wout[j];
    }

#pragma unroll
    for (int mi = 0; mi < 4; mi++) {
#pragma unroll
        for (int r = 0; r < 4; r++) {
            const int b = blockB + waveM * 64 + mi * 16 + quad * 4 + r;
            const float x = predbuf_r[b];  // pred_{t-1} (incl. b_out) or 0 at t=0
            float pacc = 0.0f;
#pragma unroll
            for (int jh = 0; jh < 2; jh++) {
                const int j = jb2 * 64 + waveN * 32 + jh * 16 + l15;
                const float gi = acc[mi][0 + jh][r] + x * wihv[jh][0] + bsvv[jh][0];
                const float gf = acc[mi][2 + jh][r] + x * wihv[jh][1] + bsvv[jh][1];
                const float gg = acc[mi][4 + jh][r] + x * wihv[jh][2] + bsvv[jh][2];
                const float go = acc[mi][6 + jh][r] + x * wihv[jh][3] + bsvv[jh][3];
                const float cn = fast_sigmoid(gf) * cin[(size_t)b * HH + j]
                               + fast_sigmoid(gi) * fast_tanh(gg);
                cout[(size_t)b * HH + j] = cn;
                const float hn = fast_sigmoid(go) * fast_tanh(cn);
                hwrite[(size_t)b * HH + j] = (bf16)hn;
                pacc += hn * wov[jh];
            }
            pacc += __shfl_xor(pacc, 1);
            pacc += __shfl_xor(pacc, 2);
            pacc += __shfl_xor(pacc, 4);
            pacc += __shfl_xor(pacc, 8);
            if (l15 == 0) atomicAdd(&predbuf_w[b], pacc);
        }
    }
}

// ---- Output transpose: out[b][t] = pred_t[b] ------------------------------

__global__ void write_out(const float* __restrict__ predbuf, float* __restrict__ out) {
    int idx = blockIdx.x * blockDim.x + threadIdx.x;
    if (idx < BB * TT) {
        int t = idx & (TT - 1);
        int b = idx >> 7;
        out[idx] = predbuf[(size_t)(t + 1) * BB + b];
    }
}

// ---- Host launch -----------------------------------------------------------

extern "C" void kernel_launch(void* const* d_in, const int* in_sizes, int n_in,
                              void* d_out, int out_size, void* d_ws, size_t ws_size,
                              hipStream_t stream) {
    const float* hidden = (const float*)d_in[0];
    const float* cell   = (const float*)d_in[1];
    const float* Wih    = (const float*)d_in[2];
    const float* Whh    = (const float*)d_in[3];
    const float* bih    = (const float*)d_in[4];
    const float* bhh    = (const float*)d_in[5];
    const float* Wout   = (const float*)d_in[6];
    const float* bout   = (const float*)d_in[7];
    float* out = (float*)d_out;

    char* ws = (char*)d_ws;
    bf16* Wr = (bf16*)ws;        ws += (size_t)4 * HH * HH * 2;   // 8 MB
    bf16* hb0 = (bf16*)ws;       ws += (size_t)BB * HH * 2;       // 8 MB
    bf16* hb1 = (bf16*)ws;       ws += (size_t)BB * HH * 2;       // 8 MB
    float* cbuf = (float*)ws;    ws += (size_t)BB * HH * 4;       // 16 MB
    float* bias = (float*)ws;    ws += (size_t)4 * HH * 4;        // 16 KB
    float* predbuf = (float*)ws; ws += (size_t)(TT + 1) * BB * 4; // 2.1 MB

    prep_weights<<<(4 * HH * HH + 255) / 256, 256, 0, stream>>>(Whh, bih, bhh, Wr, bias);
    prep_h<<<(BB * HH + 255) / 256, 256, 0, stream>>>(hidden, hb0);
    prep_pred<<<((TT + 1) * BB + 255) / 256, 256, 0, stream>>>(predbuf, bout);

    bf16* hb[2] = {hb0, hb1};
    for (int t = 0; t < TT; t++) {
        const bf16* hr = hb[t & 1];
        bf16* hw = hb[(t + 1) & 1];
        const float* ci = (t == 0) ? cell : cbuf;
        lstm_step<<<16 * (BB / BM), 256, 0, stream>>>(
            hr, hw, ci, cbuf, Wr, bias, Wih, Wout,
            predbuf + (size_t)t * BB, predbuf + (size_t)(t + 1) * BB);
    }

    write_out<<<(BB * TT + 255) / 256, 256, 0, stream>>>(predbuf, out);
}